// Round 1
// baseline (500.122 us; speedup 1.0000x reference)
//
#include <hip/hip_runtime.h>

typedef unsigned short u16;
typedef unsigned int   u32;
typedef float f32x4 __attribute__((ext_vector_type(4)));
typedef int   i32x4 __attribute__((ext_vector_type(4)));
typedef int   i32x2 __attribute__((ext_vector_type(2)));

// ---------- helpers ----------
__device__ inline u16 f2bf(float f) {
  u32 u = __float_as_uint(f);
  return (u16)((u + 0x7FFFu + ((u >> 16) & 1u)) >> 16);
}
__device__ inline float bflo(int u) { return __uint_as_float(((u32)u) << 16); }
__device__ inline float bfhi(int u) { return __uint_as_float(((u32)u) & 0xFFFF0000u); }
__device__ inline float bf2f(u16 h) { return __uint_as_float(((u32)h) << 16); }

__device__ inline u32 fkey(float f) {  // order-preserving float->uint
  u32 u = __float_as_uint(f);
  return (u & 0x80000000u) ? ~u : (u | 0x80000000u);
}
__device__ inline float unkey(u32 k) {
  u32 u = (k & 0x80000000u) ? (k & 0x7FFFFFFFu) : ~k;
  return __uint_as_float(u);
}

struct MlpP { const float *W1,*b1,*g1,*bb1,*W2,*b2,*g2,*bb2,*W3,*b3; };

// 5 -> 16(LN,tanh) -> 8(LN,tanh) -> 3(sigmoid)
__device__ inline void mlp_eval(const MlpP& p, const float* s, float* ctl) {
  float h1[16];
  float mu = 0.f;
  #pragma unroll
  for (int i = 0; i < 16; ++i) {
    float v = p.b1[i];
    #pragma unroll
    for (int k = 0; k < 5; ++k) v = fmaf(p.W1[i*5+k], s[k], v);
    h1[i] = v; mu += v;
  }
  mu *= (1.0f/16.0f);
  float vv = 0.f;
  #pragma unroll
  for (int i = 0; i < 16; ++i) { float d = h1[i]-mu; vv += d*d; }
  vv *= (1.0f/16.0f);
  float inv = 1.0f/sqrtf(vv + 1e-5f);
  #pragma unroll
  for (int i = 0; i < 16; ++i) h1[i] = tanhf((h1[i]-mu)*inv*p.g1[i] + p.bb1[i]);
  float h2[8];
  mu = 0.f;
  #pragma unroll
  for (int o = 0; o < 8; ++o) {
    float v = p.b2[o];
    #pragma unroll
    for (int i = 0; i < 16; ++i) v = fmaf(p.W2[o*16+i], h1[i], v);
    h2[o] = v; mu += v;
  }
  mu *= 0.125f;
  vv = 0.f;
  #pragma unroll
  for (int o = 0; o < 8; ++o) { float d = h2[o]-mu; vv += d*d; }
  vv *= 0.125f;
  inv = 1.0f/sqrtf(vv + 1e-5f);
  #pragma unroll
  for (int o = 0; o < 8; ++o) h2[o] = tanhf((h2[o]-mu)*inv*p.g2[o] + p.bb2[o]);
  #pragma unroll
  for (int c = 0; c < 3; ++c) {
    float v = p.b3[c];
    #pragma unroll
    for (int o = 0; o < 8; ++o) v = fmaf(p.W3[c*8+o], h2[o], v);
    ctl[c] = 1.0f/(1.0f + __expf(-v));
  }
}

// ---------- K0: f32 -> bf16 cast ----------
__global__ __launch_bounds__(256) void k_cast(const float* __restrict__ in,
                                              u16* __restrict__ out, int n) {
  int i = (blockIdx.x * 256 + threadIdx.x) * 4;
  if (i < n) {
    f32x4 v = *(const f32x4*)(in + i);
    u16 o[4] = { f2bf(v[0]), f2bf(v[1]), f2bf(v[2]), f2bf(v[3]) };
    *(u32*)(out + i)     = ((u32)o[1] << 16) | o[0];
    *(u32*)(out + i + 2) = ((u32)o[3] << 16) | o[2];
  }
}

// ---------- K0b: init stats accumulators ----------
__global__ void k_init(float* S) {
  int t = threadIdx.x;
  if (t < 3) S[t] = 0.f;
  if (t == 3) ((u32*)S)[3] = 0xFFFFFFFFu;  // min key
  if (t == 4) ((u32*)S)[4] = 0u;           // max key
}

// ---------- K1: e = x @ W_embed.T + b_embed (bf16 MFMA, e stored bf16) ----------
// M=N=4096, K=256. 128x128 tile, 4 waves (2x2), each wave 64x64 = 4x4 frags.
__global__ __launch_bounds__(256) void k_gemm(const u16* __restrict__ Xb,
                                              const u16* __restrict__ Wb,
                                              const float* __restrict__ bias,
                                              u16* __restrict__ E) {
  __shared__ u16 As[128][40];   // row stride 80B = 5*16B: keeps 16B alignment
  __shared__ u16 Bs[128][40];
  const int t = threadIdx.x;
  const int wv = t >> 6, lane = t & 63;
  const int wr = wv >> 1, wc = wv & 1;
  const int i0 = blockIdx.y * 128, j0 = blockIdx.x * 128;
  const int rr = lane & 15;
  const int g4 = (lane >> 4) * 4;
  f32x4 acc[4][4] = {};
  for (int k0 = 0; k0 < 256; k0 += 32) {
    #pragma unroll
    for (int r = 0; r < 2; ++r) {
      int li = r * 256 + t;
      int row = li >> 2, ch = li & 3;
      *(i32x4*)(&As[row][ch*8]) = *(const i32x4*)(Xb + (i0+row)*256 + k0 + ch*8);
      *(i32x4*)(&Bs[row][ch*8]) = *(const i32x4*)(Wb + (j0+row)*256 + k0 + ch*8);
    }
    __syncthreads();
    i32x2 a0[4], a1[4], b0[4], b1[4];
    #pragma unroll
    for (int m = 0; m < 4; ++m) {
      a0[m] = *(const i32x2*)(&As[wr*64 + m*16 + rr][g4]);
      a1[m] = *(const i32x2*)(&As[wr*64 + m*16 + rr][16 + g4]);
    }
    #pragma unroll
    for (int n = 0; n < 4; ++n) {
      b0[n] = *(const i32x2*)(&Bs[wc*64 + n*16 + rr][g4]);
      b1[n] = *(const i32x2*)(&Bs[wc*64 + n*16 + rr][16 + g4]);
    }
    #pragma unroll
    for (int m = 0; m < 4; ++m)
      #pragma unroll
      for (int n = 0; n < 4; ++n) {
        asm volatile("v_mfma_f32_16x16x16_bf16 %0, %1, %2, %0"
                     : "+v"(acc[m][n]) : "v"(a0[m]), "v"(b0[n]));
        asm volatile("v_mfma_f32_16x16x16_bf16 %0, %1, %2, %0"
                     : "+v"(acc[m][n]) : "v"(a1[m]), "v"(b1[n]));
      }
    __syncthreads();
  }
  asm volatile("s_nop 7\ns_nop 7" ::: "memory");  // MFMA -> VALU read hazard
  const int cq = lane & 15, rq = (lane >> 4) * 4;
  #pragma unroll
  for (int n = 0; n < 4; ++n) {
    int col = j0 + wc*64 + n*16 + cq;
    float bv = bias[col];
    #pragma unroll
    for (int m = 0; m < 4; ++m) {
      int rowb = i0 + wr*64 + m*16 + rq;
      #pragma unroll
      for (int r = 0; r < 4; ++r)
        E[(size_t)(rowb + r)*4096 + col] = f2bf(acc[m][n][r] + bv);
    }
  }
}

// ---------- K2a: global reductions over e (sum, sumsq, sumabs, min, max) ----------
__global__ __launch_bounds__(256) void k_reduce_e(const u16* __restrict__ E,
                                                  float* __restrict__ S) {
  const int t = threadIdx.x;
  size_t base = (size_t)blockIdx.x * 8192 + (size_t)t * 8;
  float s = 0.f, ss = 0.f, sa = 0.f, mn = 1e30f, mx = -1e30f;
  #pragma unroll
  for (int r = 0; r < 4; ++r) {
    i32x4 v = *(const i32x4*)(E + base + r*2048);
    #pragma unroll
    for (int q = 0; q < 4; ++q) {
      float f0 = bflo(v[q]), f1 = bfhi(v[q]);
      s += f0 + f1;
      ss = fmaf(f0, f0, ss); ss = fmaf(f1, f1, ss);
      sa += fabsf(f0) + fabsf(f1);
      mn = fminf(mn, fminf(f0, f1));
      mx = fmaxf(mx, fmaxf(f0, f1));
    }
  }
  #pragma unroll
  for (int off = 32; off; off >>= 1) {
    s += __shfl_xor(s, off); ss += __shfl_xor(ss, off); sa += __shfl_xor(sa, off);
    mn = fminf(mn, __shfl_xor(mn, off));
    mx = fmaxf(mx, __shfl_xor(mx, off));
  }
  __shared__ float W5[4][5];
  const int wv = t >> 6, lane = t & 63;
  if (lane == 0) { W5[wv][0]=s; W5[wv][1]=ss; W5[wv][2]=sa; W5[wv][3]=mn; W5[wv][4]=mx; }
  __syncthreads();
  if (t == 0) {
    float S0=0,S1=0,S2=0,Mn=1e30f,Mx=-1e30f;
    #pragma unroll
    for (int w = 0; w < 4; ++w) {
      S0+=W5[w][0]; S1+=W5[w][1]; S2+=W5[w][2];
      Mn=fminf(Mn,W5[w][3]); Mx=fmaxf(Mx,W5[w][4]);
    }
    atomicAdd(&S[0], S0); atomicAdd(&S[1], S1); atomicAdd(&S[2], S2);
    atomicMin((u32*)S + 3, fkey(Mn));
    atomicMax((u32*)S + 4, fkey(Mx));
  }
}

// ---------- K2b: t-regulator -> ap -> normalized sparse adjacency ----------
__global__ __launch_bounds__(256) void k_prep(const float* __restrict__ adjw,
    const float* __restrict__ Wslow,
    const float* tW1, const float* tb1, const float* tg1, const float* tbb1,
    const float* tW2, const float* tb2, const float* tg2, const float* tbb2,
    const float* tW3, const float* tb3,
    float* __restrict__ S) {
  __shared__ float red[2][256];
  __shared__ float apL;
  const int t = threadIdx.x;
  float a = 0.f, w = 0.f;
  for (int i = t; i < 4096; i += 256) {
    float v = adjw[i]; a = fmaf(v, v, a);
    float u = Wslow[i]; w = fmaf(u, u, w);
  }
  red[0][t] = a; red[1][t] = w;
  __syncthreads();
  for (int sred = 128; sred > 0; sred >>= 1) {
    if (t < sred) { red[0][t] += red[0][t+sred]; red[1][t] += red[1][t+sred]; }
    __syncthreads();
  }
  if (t == 0) {
    float wn_t = sqrtf(red[0][0]);
    float wn_c = sqrtf(red[1][0]);
    S[7] = wn_c;
    const float n = 16777216.0f, n1 = 16777215.0f;
    float sum = S[0], sumsq = S[1], sumabs = S[2];
    float mean = sum / n;
    float var = (sumsq - sum*mean) / n1;             // ddof=1
    float mn = unkey(((u32*)S)[3]);
    float mx = unkey(((u32*)S)[4]);
    float sfv[5];
    sfv[0] = fabsf(var - 0.5f);                      // natural_stress
    sfv[1] = fabsf((mx - mn)/n1 - 1.0f);             // sort-free smoothness
    sfv[2] = sumabs / n;                             // excitation
    sfv[3] = wn_t;                                   // fatigue
    sfv[4] = sqrtf(sumsq / n);                       // gradient_proxy
    MlpP p{tW1,tb1,tg1,tbb1,tW2,tb2,tg2,tbb2,tW3,tb3};
    float ctl[3];
    mlp_eval(p, sfv, ctl);
    apL = ctl[0];
    S[6] = ctl[0];
  }
  __syncthreads();
  if (t < 64) {
    const int rr = t >> 3, cc = t & 7;
    const float ap = apL;
    const int nb[4] = { rr>0 ? t-8 : -1, rr<7 ? t+8 : -1, cc>0 ? t-1 : -1, cc<7 ? t+1 : -1 };
    float w4[4]; float rs = 0.f;
    #pragma unroll
    for (int q = 0; q < 4; ++q) {
      w4[q] = (nb[q] >= 0) ? 1.0f/(1.0f + __expf(-adjw[t*64 + nb[q]] * ap)) : 0.0f;
      rs += w4[q];
    }
    rs = fmaxf(rs, 1e-6f);
    #pragma unroll
    for (int q = 0; q < 4; ++q) S[8 + t*4 + q] = w4[q] / rs;
  }
}

// ---------- K3: fused message-pass + cell + readout (one block per batch row) ----------
__global__ __launch_bounds__(256) void k_cell(const u16* __restrict__ E,
    const float* __restrict__ Ws, const float* __restrict__ Wf,
    const float* __restrict__ lng, const float* __restrict__ lnb,
    const float* __restrict__ Wread, const float* __restrict__ bread,
    const float* __restrict__ S,
    const float* cW1, const float* cb1, const float* cg1, const float* cbb1,
    const float* cW2, const float* cb2, const float* cg2, const float* cbb2,
    const float* cW3, const float* cb3,
    float* __restrict__ out) {
  __shared__ float eb[64][68];    // e rows (f32); reused for hs after P2
  __shared__ float mT[64][68];    // m transposed: mT[d][n]
  __shared__ u16  WsT[64][72];    // W_slow^T bf16 [d][j]
  __shared__ u16  WfT[64][72];
  __shared__ u16  hfL[64][72];    // hf bf16 [n][j]
  __shared__ float adjcL[64][4];
  __shared__ float bg[64][2];     // beta, gate
  __shared__ float prm[308];
  __shared__ float lngL[64], lnbL[64];
  __shared__ float wavp[4][10];
  __shared__ float wncL;

  const int t = threadIdx.x;
  const int wv = t >> 6, lane = t & 63;
  const int b = blockIdx.x;
  const u16* Eb = E + (size_t)b * 4096;

  // ---- P1: loads ----
  for (int i = t; i < 512; i += 256) {
    int fe = i << 3; int n = fe >> 6, d = fe & 63;
    i32x4 v = *(const i32x4*)(Eb + fe);
    float* dst = &eb[n][d];
    dst[0]=bflo(v[0]); dst[1]=bfhi(v[0]); dst[2]=bflo(v[1]); dst[3]=bfhi(v[1]);
    dst[4]=bflo(v[2]); dst[5]=bfhi(v[2]); dst[6]=bflo(v[3]); dst[7]=bfhi(v[3]);
  }
  for (int i = t; i < 4096; i += 256) {
    int j = i >> 6, d = i & 63;
    WsT[d][j] = f2bf(Ws[i]);
    WfT[d][j] = f2bf(Wf[i]);
  }
  ((float*)adjcL)[t] = S[8 + t];
  for (int i = t; i < 80;  i += 256) prm[i] = cW1[i];
  if (t < 16) { prm[80+t]=cb1[t]; prm[96+t]=cg1[t]; prm[112+t]=cbb1[t]; }
  for (int i = t; i < 128; i += 256) prm[128+i] = cW2[i];
  if (t < 8)  { prm[256+t]=cb2[t]; prm[264+t]=cg2[t]; prm[272+t]=cbb2[t]; }
  if (t < 24) prm[280+t] = cW3[t];
  if (t < 3)  prm[304+t] = cb3[t];
  if (t < 64) { lngL[t] = lng[t]; lnbL[t] = lnb[t]; }
  if (t == 0) wncL = S[7];
  __syncthreads();

  // ---- P2: message passing, m^T[d][n] = sum_q adj[n][q] * e[nb_q][d] ----
  {
    const int d = lane;
    #pragma unroll
    for (int i = 0; i < 16; ++i) {
      const int n = wv + (i << 2);
      const int rr = n >> 3, cc = n & 7;
      const int nb0 = rr > 0 ? n - 8 : 0;
      const int nb1 = rr < 7 ? n + 8 : 0;
      const int nb2 = cc > 0 ? n - 1 : 0;
      const int nb3 = cc < 7 ? n + 1 : 0;
      float acc = adjcL[n][0]*eb[nb0][d] + adjcL[n][1]*eb[nb1][d]
                + adjcL[n][2]*eb[nb2][d] + adjcL[n][3]*eb[nb3][d];
      mT[d][n] = acc;
    }
  }
  __syncthreads();

  // ---- P4: hs = m @ Ws^T, hf = m @ Wf^T (register-tiled 4x4); hs -> eb, hf -> hfL ----
  {
    const int n0 = (t >> 4) * 4, j0 = (t & 15) * 4;
    float a_s[4][4] = {};
    float a_f[4][4] = {};
    #pragma unroll 4
    for (int kk = 0; kk < 64; ++kk) {
      f32x4 mv = *(const f32x4*)(&mT[kk][n0]);
      i32x2 wsv = *(const i32x2*)(&WsT[kk][j0]);
      i32x2 wfv = *(const i32x2*)(&WfT[kk][j0]);
      float ws4[4] = { bflo(wsv[0]), bfhi(wsv[0]), bflo(wsv[1]), bfhi(wsv[1]) };
      float wf4[4] = { bflo(wfv[0]), bfhi(wfv[0]), bflo(wfv[1]), bfhi(wfv[1]) };
      #pragma unroll
      for (int ni = 0; ni < 4; ++ni)
        #pragma unroll
        for (int ji = 0; ji < 4; ++ji) {
          a_s[ni][ji] = fmaf(mv[ni], ws4[ji], a_s[ni][ji]);
          a_f[ni][ji] = fmaf(mv[ni], wf4[ji], a_f[ni][ji]);
        }
    }
    __syncthreads();  // everyone done reading eb (P2) before overwrite? (P2 already barriered; this orders hs writes)
    #pragma unroll
    for (int ni = 0; ni < 4; ++ni)
      #pragma unroll
      for (int ji = 0; ji < 4; ++ji) {
        eb[n0+ni][j0+ji] = a_s[ni][ji];
        hfL[n0+ni][j0+ji] = f2bf(a_f[ni][ji]);
      }
  }
  __syncthreads();

  // ---- P5 (wave 0): per-row stats + regulator MLP -> beta/gate ----
  if (wv == 0) {
    const int n = lane;
    float s1=0.f, s2=0.f, mn=1e30f, mx=-1e30f, sa=0.f, sq=0.f;
    #pragma unroll 8
    for (int d = 0; d < 64; ++d) {
      float v = mT[d][n];
      s1 += v; s2 = fmaf(v, v, s2);
      mn = fminf(mn, v); mx = fmaxf(mx, v);
      float h = eb[n][d];   // hs
      sa += fabsf(h); sq = fmaf(h, h, sq);
    }
    float var = (s2 - s1*s1*(1.0f/64.0f)) * (1.0f/63.0f);  // ddof=1
    float sfv[5];
    sfv[0] = fabsf(var - 0.5f);
    sfv[1] = fabsf((mx - mn)*(1.0f/63.0f) - 1.0f);
    sfv[2] = sa * (1.0f/64.0f);
    sfv[3] = wncL;
    sfv[4] = sqrtf(sq * (1.0f/64.0f));
    MlpP p{prm, prm+80, prm+96, prm+112, prm+128, prm+256, prm+264, prm+272, prm+280, prm+304};
    float ctl[3];
    mlp_eval(p, sfv, ctl);
    bg[n][0] = 0.5f + 2.0f*ctl[1];
    bg[n][1] = ctl[2];
  }
  __syncthreads();

  // ---- P6: comb -> swish -> LN -> fused readout ----
  float racc[10];
  #pragma unroll
  for (int c = 0; c < 10; ++c) racc[c] = 0.f;
  #pragma unroll 1
  for (int i = 0; i < 16; ++i) {
    const int n = wv + (i << 2);
    float hs = eb[n][lane];
    float hf = bf2f(hfL[n][lane]);
    float beta = bg[n][0], gate = bg[n][1];
    float comb = fmaf(hf, gate, hs);
    float act = comb / (1.0f + __expf(-beta * comb));
    float s1 = act, s2 = act*act;
    #pragma unroll
    for (int off = 32; off; off >>= 1) { s1 += __shfl_xor(s1, off); s2 += __shfl_xor(s2, off); }
    float mu = s1 * (1.0f/64.0f);
    float vvv = s2 * (1.0f/64.0f) - mu*mu;   // population var (ddof=0)
    float proc = (act - mu) * (1.0f/sqrtf(vvv + 1e-5f)) * lngL[lane] + lnbL[lane];
    const float* wrp = Wread + n*64 + lane;
    #pragma unroll
    for (int c = 0; c < 10; ++c) racc[c] = fmaf(proc, wrp[c*4096], racc[c]);
  }
  #pragma unroll
  for (int c = 0; c < 10; ++c) {
    float v = racc[c];
    #pragma unroll
    for (int off = 32; off; off >>= 1) v += __shfl_xor(v, off);
    if (lane == 0) wavp[wv][c] = v;
  }
  __syncthreads();
  if (t < 10) out[(size_t)b*10 + t] = bread[t] + wavp[0][t] + wavp[1][t] + wavp[2][t] + wavp[3][t];
}

// ---------- launcher ----------
extern "C" void kernel_launch(void* const* d_in, const int* in_sizes, int n_in,
                              void* d_out, int out_size, void* d_ws, size_t ws_size,
                              hipStream_t stream) {
  (void)in_sizes; (void)n_in; (void)out_size; (void)ws_size;
  const float* x       = (const float*)d_in[0];
  const float* W_embed = (const float*)d_in[1];
  const float* b_embed = (const float*)d_in[2];
  const float* adjw    = (const float*)d_in[3];
  const float* Wslow   = (const float*)d_in[4];
  const float* Wfast   = (const float*)d_in[5];
  const float* lng     = (const float*)d_in[6];
  const float* lnb     = (const float*)d_in[7];
  const float* Wread   = (const float*)d_in[8];
  const float* bread   = (const float*)d_in[9];
  float* out = (float*)d_out;

  char* ws = (char*)d_ws;
  u16*   Ebf = (u16*)ws;                               // 4096*4096*2 = 33554432 B
  u16*   Xbf = (u16*)(ws + 33554432);                  // 2097152 B
  u16*   Wbf = (u16*)(ws + 35651584);                  // 2097152 B
  float* S   = (float*)(ws + 37748736);                // stats + adjc

  hipLaunchKernelGGL(k_cast, dim3(1024), dim3(256), 0, stream, x, Xbf, 1048576);
  hipLaunchKernelGGL(k_cast, dim3(1024), dim3(256), 0, stream, W_embed, Wbf, 1048576);
  hipLaunchKernelGGL(k_init, dim3(1), dim3(64), 0, stream, S);
  hipLaunchKernelGGL(k_gemm, dim3(32, 32), dim3(256), 0, stream, Xbf, Wbf, b_embed, Ebf);
  hipLaunchKernelGGL(k_reduce_e, dim3(2048), dim3(256), 0, stream, Ebf, S);
  hipLaunchKernelGGL(k_prep, dim3(1), dim3(256), 0, stream, adjw, Wslow,
                     (const float*)d_in[10], (const float*)d_in[11], (const float*)d_in[12], (const float*)d_in[13],
                     (const float*)d_in[14], (const float*)d_in[15], (const float*)d_in[16], (const float*)d_in[17],
                     (const float*)d_in[18], (const float*)d_in[19], S);
  hipLaunchKernelGGL(k_cell, dim3(4096), dim3(256), 0, stream, Ebf, Wslow, Wfast, lng, lnb,
                     Wread, bread, S,
                     (const float*)d_in[20], (const float*)d_in[21], (const float*)d_in[22], (const float*)d_in[23],
                     (const float*)d_in[24], (const float*)d_in[25], (const float*)d_in[26], (const float*)d_in[27],
                     (const float*)d_in[28], (const float*)d_in[29], out);
}

// Round 2
// 332.784 us; speedup vs baseline: 1.5028x; 1.5028x over previous
//
#include <hip/hip_runtime.h>

typedef unsigned short u16;
typedef unsigned int   u32;
typedef float f32x4 __attribute__((ext_vector_type(4)));
typedef int   i32x4 __attribute__((ext_vector_type(4)));
typedef int   i32x2 __attribute__((ext_vector_type(2)));
typedef short s8v   __attribute__((ext_vector_type(8)));

// ---------- helpers ----------
__device__ inline u16 f2bf(float f) {
  u32 u = __float_as_uint(f);
  return (u16)((u + 0x7FFFu + ((u >> 16) & 1u)) >> 16);
}
__device__ inline float bf2f(u16 h) { return __uint_as_float(((u32)h) << 16); }
__device__ inline float bflo(int u) { return __uint_as_float(((u32)u) << 16); }
__device__ inline float bfhi(int u) { return __uint_as_float(((u32)u) & 0xFFFF0000u); }

__device__ inline u32 fkey(float f) {
  u32 u = __float_as_uint(f);
  return (u & 0x80000000u) ? ~u : (u | 0x80000000u);
}
__device__ inline float unkey(u32 k) {
  u32 u = (k & 0x80000000u) ? (k & 0x7FFFFFFFu) : ~k;
  return __uint_as_float(u);
}
__device__ inline float fast_tanh(float x) {
  float cx = fminf(fmaxf(x, -15.f), 15.f);
  float e = __expf(2.f * cx);
  return __fdividef(e - 1.f, e + 1.f);
}
__device__ inline float sigm(float x) { return __fdividef(1.f, 1.f + __expf(-x)); }

__device__ inline void gload_lds16(const u16* g, u16* l) {
  __builtin_amdgcn_global_load_lds((const __attribute__((address_space(1))) u32*)g,
                                   (__attribute__((address_space(3))) u32*)l, 16, 0, 0);
}

struct MlpP { const float *W1,*b1,*g1,*bb1,*W2,*b2,*g2,*bb2,*W3,*b3; };

// 5 -> 16(LN,tanh) -> 8(LN,tanh) -> 3(sigmoid)
__device__ inline void mlp_eval(const MlpP& p, const float* s, float* ctl) {
  float h1[16];
  float mu = 0.f;
  #pragma unroll
  for (int i = 0; i < 16; ++i) {
    float v = p.b1[i];
    #pragma unroll
    for (int k = 0; k < 5; ++k) v = fmaf(p.W1[i*5+k], s[k], v);
    h1[i] = v; mu += v;
  }
  mu *= (1.0f/16.0f);
  float vv = 0.f;
  #pragma unroll
  for (int i = 0; i < 16; ++i) { float d = h1[i]-mu; vv += d*d; }
  vv *= (1.0f/16.0f);
  float inv = 1.0f/sqrtf(vv + 1e-5f);
  #pragma unroll
  for (int i = 0; i < 16; ++i) h1[i] = fast_tanh((h1[i]-mu)*inv*p.g1[i] + p.bb1[i]);
  float h2[8];
  mu = 0.f;
  #pragma unroll
  for (int o = 0; o < 8; ++o) {
    float v = p.b2[o];
    #pragma unroll
    for (int i = 0; i < 16; ++i) v = fmaf(p.W2[o*16+i], h1[i], v);
    h2[o] = v; mu += v;
  }
  mu *= 0.125f;
  vv = 0.f;
  #pragma unroll
  for (int o = 0; o < 8; ++o) { float d = h2[o]-mu; vv += d*d; }
  vv *= 0.125f;
  inv = 1.0f/sqrtf(vv + 1e-5f);
  #pragma unroll
  for (int o = 0; o < 8; ++o) h2[o] = fast_tanh((h2[o]-mu)*inv*p.g2[o] + p.bb2[o]);
  #pragma unroll
  for (int c = 0; c < 3; ++c) {
    float v = p.b3[c];
    #pragma unroll
    for (int o = 0; o < 8; ++o) v = fmaf(p.W3[c*8+o], h2[o], v);
    ctl[c] = sigm(v);
  }
}

// ---------- K0: f32 -> bf16 cast ----------
__global__ __launch_bounds__(256) void k_cast(const float* __restrict__ in,
                                              u16* __restrict__ out, int n) {
  int i = (blockIdx.x * 256 + threadIdx.x) * 4;
  if (i < n) {
    f32x4 v = *(const f32x4*)(in + i);
    u16 o[4] = { f2bf(v[0]), f2bf(v[1]), f2bf(v[2]), f2bf(v[3]) };
    *(u32*)(out + i)     = ((u32)o[1] << 16) | o[0];
    *(u32*)(out + i + 2) = ((u32)o[3] << 16) | o[2];
  }
}

// ---------- K0b: init stats accumulators ----------
__global__ void k_init(float* S) {
  int t = threadIdx.x;
  if (t < 3) S[t] = 0.f;
  if (t == 3) ((u32*)S)[3] = 0xFFFFFFFFu;  // min key
  if (t == 4) ((u32*)S)[4] = 0u;           // max key
}

// ---------- K1: e = x @ W_embed.T + b_embed, fused global stats ----------
// m97 structure: 128x128 tile, BK=64, global_load_lds w=16, 16x16x32 bf16 MFMA.
__global__ __launch_bounds__(256) void k_gemm(const u16* __restrict__ Xb,
                                              const u16* __restrict__ Wb,
                                              const float* __restrict__ bias,
                                              u16* __restrict__ E,
                                              float* __restrict__ S) {
  __shared__ __align__(16) u16 As[128*64];
  __shared__ __align__(16) u16 Bs[128*64];
  const int t = threadIdx.x;
  const int wv = t >> 6, lane = t & 63;
  const int wr = wv >> 1, wc = wv & 1;
  const int i0 = blockIdx.y * 128, j0 = blockIdx.x * 128;
  const int rr = lane & 15, q = lane >> 4;
  const int lrow = lane >> 3, lcol = (lane & 7) * 8;
  f32x4 acc[4][4] = {};
  for (int k0 = 0; k0 < 256; k0 += 64) {
    #pragma unroll
    for (int r = 0; r < 4; ++r) {
      const int row = (r*4 + wv)*8 + lrow;     // lds chunk per (r,wave): 1KB, lane*16B
      gload_lds16(Xb + (size_t)(i0 + row)*256 + k0 + lcol, &As[(r*4 + wv)*512]);
      gload_lds16(Wb + (size_t)(j0 + row)*256 + k0 + lcol, &Bs[(r*4 + wv)*512]);
    }
    __syncthreads();
    #pragma unroll
    for (int ks = 0; ks < 2; ++ks) {
      s8v a[4], b[4];
      #pragma unroll
      for (int m = 0; m < 4; ++m) a[m] = *(const s8v*)&As[(wr*64 + m*16 + rr)*64 + ks*32 + q*8];
      #pragma unroll
      for (int n = 0; n < 4; ++n) b[n] = *(const s8v*)&Bs[(wc*64 + n*16 + rr)*64 + ks*32 + q*8];
      #pragma unroll
      for (int m = 0; m < 4; ++m)
        #pragma unroll
        for (int n = 0; n < 4; ++n)
          acc[m][n] = __builtin_amdgcn_mfma_f32_16x16x32_bf16(a[m], b[n], acc[m][n], 0, 0, 0);
    }
    __syncthreads();
  }
  // epilogue: bias + store bf16 + global stats on f32 values
  float s = 0.f, ss = 0.f, sa = 0.f, mnv = 1e30f, mxv = -1e30f;
  #pragma unroll
  for (int n = 0; n < 4; ++n) {
    const int col = j0 + wc*64 + n*16 + rr;
    const float bv = bias[col];
    #pragma unroll
    for (int m = 0; m < 4; ++m) {
      const int rowb = i0 + wr*64 + m*16 + q*4;
      #pragma unroll
      for (int r = 0; r < 4; ++r) {
        float v = acc[m][n][r] + bv;
        E[(size_t)(rowb + r)*4096 + col] = f2bf(v);
        s += v; ss = fmaf(v, v, ss); sa += fabsf(v);
        mnv = fminf(mnv, v); mxv = fmaxf(mxv, v);
      }
    }
  }
  #pragma unroll
  for (int off = 32; off; off >>= 1) {
    s += __shfl_xor(s, off); ss += __shfl_xor(ss, off); sa += __shfl_xor(sa, off);
    mnv = fminf(mnv, __shfl_xor(mnv, off));
    mxv = fmaxf(mxv, __shfl_xor(mxv, off));
  }
  __shared__ float red5[4][5];
  if (lane == 0) { red5[wv][0]=s; red5[wv][1]=ss; red5[wv][2]=sa; red5[wv][3]=mnv; red5[wv][4]=mxv; }
  __syncthreads();
  if (t == 0) {
    float S0 = red5[0][0]+red5[1][0]+red5[2][0]+red5[3][0];
    float S1 = red5[0][1]+red5[1][1]+red5[2][1]+red5[3][1];
    float S2 = red5[0][2]+red5[1][2]+red5[2][2]+red5[3][2];
    float Mn = fminf(fminf(red5[0][3],red5[1][3]), fminf(red5[2][3],red5[3][3]));
    float Mx = fmaxf(fmaxf(red5[0][4],red5[1][4]), fmaxf(red5[2][4],red5[3][4]));
    atomicAdd(&S[0], S0); atomicAdd(&S[1], S1); atomicAdd(&S[2], S2);
    atomicMin((u32*)S + 3, fkey(Mn));
    atomicMax((u32*)S + 4, fkey(Mx));
  }
}

// ---------- K2: t-regulator -> ap -> normalized sparse adjacency ----------
__global__ __launch_bounds__(256) void k_prep(const float* __restrict__ adjw,
    const float* __restrict__ Wslow,
    const float* tW1, const float* tb1, const float* tg1, const float* tbb1,
    const float* tW2, const float* tb2, const float* tg2, const float* tbb2,
    const float* tW3, const float* tb3,
    float* __restrict__ S) {
  __shared__ float red[2][256];
  __shared__ float apL;
  const int t = threadIdx.x;
  float a = 0.f, w = 0.f;
  for (int i = t; i < 4096; i += 256) {
    float v = adjw[i]; a = fmaf(v, v, a);
    float u = Wslow[i]; w = fmaf(u, u, w);
  }
  red[0][t] = a; red[1][t] = w;
  __syncthreads();
  for (int sred = 128; sred > 0; sred >>= 1) {
    if (t < sred) { red[0][t] += red[0][t+sred]; red[1][t] += red[1][t+sred]; }
    __syncthreads();
  }
  if (t == 0) {
    float wn_t = sqrtf(red[0][0]);
    float wn_c = sqrtf(red[1][0]);
    S[7] = wn_c;
    const float n = 16777216.0f, n1 = 16777215.0f;
    float sum = S[0], sumsq = S[1], sumabs = S[2];
    float mean = sum / n;
    float var = (sumsq - sum*mean) / n1;             // ddof=1
    float mn = unkey(((u32*)S)[3]);
    float mx = unkey(((u32*)S)[4]);
    float sfv[5];
    sfv[0] = fabsf(var - 0.5f);
    sfv[1] = fabsf((mx - mn)/n1 - 1.0f);             // sort-free smoothness
    sfv[2] = sumabs / n;
    sfv[3] = wn_t;
    sfv[4] = sqrtf(sumsq / n);
    MlpP p{tW1,tb1,tg1,tbb1,tW2,tb2,tg2,tbb2,tW3,tb3};
    float ctl[3];
    mlp_eval(p, sfv, ctl);
    apL = ctl[0];
    S[6] = ctl[0];
  }
  __syncthreads();
  if (t < 64) {
    const int rr = t >> 3, cc = t & 7;
    const float ap = apL;
    const int nb[4] = { rr>0 ? t-8 : -1, rr<7 ? t+8 : -1, cc>0 ? t-1 : -1, cc<7 ? t+1 : -1 };
    float w4[4]; float rs = 0.f;
    #pragma unroll
    for (int qq = 0; qq < 4; ++qq) {
      w4[qq] = (nb[qq] >= 0) ? sigm(adjw[t*64 + nb[qq]] * ap) : 0.0f;
      rs += w4[qq];
    }
    rs = fmaxf(rs, 1e-6f);
    #pragma unroll
    for (int qq = 0; qq < 4; ++qq) S[8 + t*4 + qq] = w4[qq] / rs;
  }
}

// ---------- K3: fused message-pass + cell + readout (one block per batch row) ----------
// hsT = Ws @ m^T via MFMA; all stats from register fragments; no serial phase.
__global__ __launch_bounds__(256) void k_cell(const u16* __restrict__ E,
    const float* __restrict__ Ws, const float* __restrict__ Wf,
    const float* __restrict__ lng, const float* __restrict__ lnb,
    const float* __restrict__ Wread, const float* __restrict__ bread,
    const float* __restrict__ S,
    const float* cW1, const float* cb1, const float* cg1, const float* cbb1,
    const float* cW2, const float* cb2, const float* cg2, const float* cbb2,
    const float* cW3, const float* cb3,
    float* __restrict__ out) {
  __shared__ __align__(16) u16 ebh[64][72];   // e bf16
  __shared__ __align__(16) u16 mh[64][72];    // m bf16
  __shared__ __align__(16) u16 WsH[64][72];   // W_slow bf16 [j][d]
  __shared__ __align__(16) u16 WfH[64][72];
  __shared__ __align__(16) float adjcL[256];
  __shared__ __align__(16) float prm[308];
  __shared__ __align__(16) float lngL[64], lnbL[64];
  __shared__ float wavp[4][10];
  __shared__ float wncL;

  const int t = threadIdx.x;
  const int wv = t >> 6, lane = t & 63;
  const int b = blockIdx.x;
  const u16* Eb = E + (size_t)b * 4096;

  // ---- P1: loads ----
  #pragma unroll
  for (int r = 0; r < 2; ++r) {               // e: 512 chunks of 8 bf16
    int c = t + r*256;
    int n = c >> 3, d8 = (c & 7) * 8;
    *(i32x4*)&ebh[n][d8] = *(const i32x4*)(Eb + n*64 + d8);
  }
  #pragma unroll
  for (int r = 0; r < 4; ++r) {               // Ws/Wf: 1024 chunks of 4 f32 -> bf16
    int c = t + r*256;
    int n = c >> 4, d = (c & 15) * 4;
    f32x4 vs = *(const f32x4*)(Ws + c*4);
    f32x4 vf = *(const f32x4*)(Wf + c*4);
    i32x2 ps = { (int)((((u32)f2bf(vs[1]))<<16) | f2bf(vs[0])),
                 (int)((((u32)f2bf(vs[3]))<<16) | f2bf(vs[2])) };
    i32x2 pf = { (int)((((u32)f2bf(vf[1]))<<16) | f2bf(vf[0])),
                 (int)((((u32)f2bf(vf[3]))<<16) | f2bf(vf[2])) };
    *(i32x2*)&WsH[n][d] = ps;
    *(i32x2*)&WfH[n][d] = pf;
  }
  adjcL[t] = S[8 + t];
  for (int i = t; i < 80;  i += 256) prm[i] = cW1[i];
  if (t < 16) { prm[80+t]=cb1[t]; prm[96+t]=cg1[t]; prm[112+t]=cbb1[t]; }
  for (int i = t; i < 128; i += 256) prm[128+i] = cW2[i];
  if (t < 8)  { prm[256+t]=cb2[t]; prm[264+t]=cg2[t]; prm[272+t]=cbb2[t]; }
  if (t < 24) prm[280+t] = cW3[t];
  if (t < 3)  prm[304+t] = cb3[t];
  if (t < 64) { lngL[t] = lng[t]; lnbL[t] = lnb[t]; }
  if (t == 0) wncL = S[7];
  __syncthreads();

  // ---- P2: message passing -> mh[n][d], wave wv owns nodes wv*16..wv*16+15 ----
  {
    const int d = lane;
    #pragma unroll
    for (int i = 0; i < 16; ++i) {
      const int n = wv*16 + i;
      const int gr = n >> 3, gc = n & 7;
      const int nb0 = gr > 0 ? n - 8 : 0;
      const int nb1 = gr < 7 ? n + 8 : 0;
      const int nb2 = gc > 0 ? n - 1 : 0;
      const int nb3 = gc < 7 ? n + 1 : 0;
      float acc = adjcL[n*4+0]*bf2f(ebh[nb0][d]) + adjcL[n*4+1]*bf2f(ebh[nb1][d])
                + adjcL[n*4+2]*bf2f(ebh[nb2][d]) + adjcL[n*4+3]*bf2f(ebh[nb3][d]);
      mh[n][d] = f2bf(acc);
    }
  }
  __syncthreads();

  // ---- P3: MFMA hsT/hfT (wave owns 64x16: j x n), frags feed stats for free ----
  const int rr = lane & 15, q = lane >> 4;
  const int n = wv*16 + rr;                    // this lane's node column
  s8v bm0 = *(const s8v*)&mh[n][q*8];          // m[n][8q..8q+7]
  s8v bm1 = *(const s8v*)&mh[n][32 + q*8];     // m[n][32+8q..]
  f32x4 hs[4], hf[4];
  #pragma unroll
  for (int jt = 0; jt < 4; ++jt) {
    const u16* wsr = &WsH[jt*16 + rr][0];
    const u16* wfr = &WfH[jt*16 + rr][0];
    s8v aw0 = *(const s8v*)(wsr + q*8), aw1 = *(const s8v*)(wsr + 32 + q*8);
    s8v af0 = *(const s8v*)(wfr + q*8), af1 = *(const s8v*)(wfr + 32 + q*8);
    f32x4 z = {0.f, 0.f, 0.f, 0.f};
    hs[jt] = __builtin_amdgcn_mfma_f32_16x16x32_bf16(aw0, bm0, z, 0, 0, 0);
    hs[jt] = __builtin_amdgcn_mfma_f32_16x16x32_bf16(aw1, bm1, hs[jt], 0, 0, 0);
    hf[jt] = __builtin_amdgcn_mfma_f32_16x16x32_bf16(af0, bm0, z, 0, 0, 0);
    hf[jt] = __builtin_amdgcn_mfma_f32_16x16x32_bf16(af1, bm1, hf[jt], 0, 0, 0);
  }

  // ---- P4: per-node stats from registers (4-lane reduce over q) ----
  float s1 = 0.f, s2 = 0.f, mnv = 1e30f, mxv = -1e30f;
  #pragma unroll
  for (int j = 0; j < 8; ++j) {
    float v0 = bf2f((u16)bm0[j]), v1 = bf2f((u16)bm1[j]);
    s1 += v0 + v1;
    s2 = fmaf(v0, v0, s2); s2 = fmaf(v1, v1, s2);
    mnv = fminf(mnv, fminf(v0, v1));
    mxv = fmaxf(mxv, fmaxf(v0, v1));
  }
  float sa = 0.f, sq = 0.f;
  #pragma unroll
  for (int jt = 0; jt < 4; ++jt)
    #pragma unroll
    for (int r = 0; r < 4; ++r) { float v = hs[jt][r]; sa += fabsf(v); sq = fmaf(v, v, sq); }
  #pragma unroll
  for (int off = 16; off <= 32; off <<= 1) {
    s1 += __shfl_xor(s1, off); s2 += __shfl_xor(s2, off);
    sa += __shfl_xor(sa, off); sq += __shfl_xor(sq, off);
    mnv = fminf(mnv, __shfl_xor(mnv, off));
    mxv = fmaxf(mxv, __shfl_xor(mxv, off));
  }
  float var = (s2 - s1*s1*(1.f/64.f)) * (1.f/63.f);   // ddof=1
  float sfv[5];
  sfv[0] = fabsf(var - 0.5f);
  sfv[1] = fabsf((mxv - mnv)*(1.f/63.f) - 1.f);
  sfv[2] = sa * (1.f/64.f);
  sfv[3] = wncL;
  sfv[4] = sqrtf(sq * (1.f/64.f));
  MlpP p{prm, prm+80, prm+96, prm+112, prm+128, prm+256, prm+264, prm+272, prm+280, prm+304};
  float ctl[3];
  mlp_eval(p, sfv, ctl);
  const float beta = 0.5f + 2.f*ctl[1], gate = ctl[2];

  // ---- P5: swish -> LN -> fused readout, all from registers ----
  float acts[4][4];
  float a1 = 0.f, a2 = 0.f;
  #pragma unroll
  for (int jt = 0; jt < 4; ++jt)
    #pragma unroll
    for (int r = 0; r < 4; ++r) {
      float comb = fmaf(hf[jt][r], gate, hs[jt][r]);
      float sv = comb * sigm(beta * comb);
      acts[jt][r] = sv;
      a1 += sv; a2 = fmaf(sv, sv, a2);
    }
  a1 += __shfl_xor(a1, 16); a2 += __shfl_xor(a2, 16);
  a1 += __shfl_xor(a1, 32); a2 += __shfl_xor(a2, 32);
  float mu = a1 * (1.f/64.f);
  float vvv = a2 * (1.f/64.f) - mu*mu;                 // ddof=0
  float inv = 1.f / sqrtf(vvv + 1e-5f);
  float racc[10];
  #pragma unroll
  for (int c = 0; c < 10; ++c) racc[c] = 0.f;
  #pragma unroll
  for (int jt = 0; jt < 4; ++jt) {
    f32x4 gv = *(const f32x4*)&lngL[jt*16 + q*4];
    f32x4 bv = *(const f32x4*)&lnbL[jt*16 + q*4];
    float pr[4];
    #pragma unroll
    for (int r = 0; r < 4; ++r) pr[r] = (acts[jt][r] - mu)*inv*gv[r] + bv[r];
    const float* wrb = Wread + n*64 + jt*16 + q*4;
    #pragma unroll
    for (int c = 0; c < 10; ++c) {
      f32x4 w = *(const f32x4*)(wrb + c*4096);
      racc[c] += pr[0]*w[0] + pr[1]*w[1] + pr[2]*w[2] + pr[3]*w[3];
    }
  }
  #pragma unroll
  for (int c = 0; c < 10; ++c) {
    float v = racc[c];
    #pragma unroll
    for (int off = 1; off < 64; off <<= 1) v += __shfl_xor(v, off);
    if (lane == 0) wavp[wv][c] = v;
  }
  __syncthreads();
  if (t < 10) out[(size_t)b*10 + t] = bread[t] + wavp[0][t] + wavp[1][t] + wavp[2][t] + wavp[3][t];
}

// ---------- launcher ----------
extern "C" void kernel_launch(void* const* d_in, const int* in_sizes, int n_in,
                              void* d_out, int out_size, void* d_ws, size_t ws_size,
                              hipStream_t stream) {
  (void)in_sizes; (void)n_in; (void)out_size; (void)ws_size;
  const float* x       = (const float*)d_in[0];
  const float* W_embed = (const float*)d_in[1];
  const float* b_embed = (const float*)d_in[2];
  const float* adjw    = (const float*)d_in[3];
  const float* Wslow   = (const float*)d_in[4];
  const float* Wfast   = (const float*)d_in[5];
  const float* lng     = (const float*)d_in[6];
  const float* lnb     = (const float*)d_in[7];
  const float* Wread   = (const float*)d_in[8];
  const float* bread   = (const float*)d_in[9];
  float* out = (float*)d_out;

  char* ws = (char*)d_ws;
  u16*   Ebf = (u16*)ws;                               // 33554432 B
  u16*   Xbf = (u16*)(ws + 33554432);                  // 2097152 B
  u16*   Wbf = (u16*)(ws + 35651584);                  // 2097152 B
  float* S   = (float*)(ws + 37748736);                // stats + adjc

  hipLaunchKernelGGL(k_cast, dim3(1024), dim3(256), 0, stream, x, Xbf, 1048576);
  hipLaunchKernelGGL(k_cast, dim3(1024), dim3(256), 0, stream, W_embed, Wbf, 1048576);
  hipLaunchKernelGGL(k_init, dim3(1), dim3(64), 0, stream, S);
  hipLaunchKernelGGL(k_gemm, dim3(32, 32), dim3(256), 0, stream, Xbf, Wbf, b_embed, Ebf, S);
  hipLaunchKernelGGL(k_prep, dim3(1), dim3(256), 0, stream, adjw, Wslow,
                     (const float*)d_in[10], (const float*)d_in[11], (const float*)d_in[12], (const float*)d_in[13],
                     (const float*)d_in[14], (const float*)d_in[15], (const float*)d_in[16], (const float*)d_in[17],
                     (const float*)d_in[18], (const float*)d_in[19], S);
  hipLaunchKernelGGL(k_cell, dim3(4096), dim3(256), 0, stream, Ebf, Wslow, Wfast, lng, lnb,
                     Wread, bread, S,
                     (const float*)d_in[20], (const float*)d_in[21], (const float*)d_in[22], (const float*)d_in[23],
                     (const float*)d_in[24], (const float*)d_in[25], (const float*)d_in[26], (const float*)d_in[27],
                     (const float*)d_in[28], (const float*)d_in[29], out);
}